// Round 1
// baseline (214.334 us; speedup 1.0000x reference)
//
#include <hip/hip_runtime.h>

#define B_ 32
#define N_ 4096
#define C_ 16
#define D_ 256
#define NSPLIT 16
#define ROWS (N_ / NSPLIT)   // 256 rows per block

// One wave processes one full row (D=256 = 64 lanes x float4).
// Mask bits are wave-uniform -> scalar branches, no divergence.
__global__ __launch_bounds__(256, 4)
void tensor_fusion_kernel(const float* __restrict__ r,
                          const float* __restrict__ v,
                          float* __restrict__ out) {
    const int b     = blockIdx.x >> 4;          // / NSPLIT
    const int chunk = blockIdx.x & (NSPLIT - 1);
    const int tid   = threadIdx.x;
    const int wave  = tid >> 6;
    const int lane  = tid & 63;
    const int d4    = lane << 2;

    const float* __restrict__ rb = r + (size_t)b * N_ * C_;
    const float* __restrict__ vb = v + (size_t)b * N_ * D_;

    float4 acc[17];
#pragma unroll
    for (int c = 0; c < 17; ++c) acc[c] = make_float4(0.f, 0.f, 0.f, 0.f);

    const int n0 = chunk * ROWS;

    // software-pipelined: prefetch next row while accumulating current
    int n = n0 + wave;
    float  rv = (lane < C_) ? rb[(size_t)n * C_ + lane] : 0.0f;
    float4 v4 = *(const float4*)(vb + (size_t)n * D_ + d4);

    for (int i = 0; i < ROWS; i += 4) {
        const int npf = n + ((i + 4 < ROWS) ? 4 : 0);   // clamp last prefetch
        const float  rvn = (lane < C_) ? rb[(size_t)npf * C_ + lane] : 0.0f;
        const float4 v4n = *(const float4*)(vb + (size_t)npf * D_ + d4);

        const unsigned long long bal = __ballot(rv >= 0.5f);
        const unsigned mask = (unsigned)bal & 0xFFFFu;
#pragma unroll
        for (int c = 0; c < 16; ++c) {
            if (mask & (1u << c)) {          // wave-uniform scalar branch
                acc[c].x += v4.x; acc[c].y += v4.y;
                acc[c].z += v4.z; acc[c].w += v4.w;
            }
        }
        if (mask == 0u) {                    // "all below" row: ~1.5e-5 prob
            acc[16].x += v4.x; acc[16].y += v4.y;
            acc[16].z += v4.z; acc[16].w += v4.w;
        }
        rv = rvn; v4 = v4n; n = npf;
    }

    // cross-wave reduction in LDS (4 waves -> 1), sequential to avoid races
    __shared__ float lds[17 * D_];
#pragma unroll
    for (int i = tid; i < 17 * D_; i += 256) lds[i] = 0.0f;
    __syncthreads();
    for (int w = 0; w < 4; ++w) {
        if (wave == w) {
#pragma unroll
            for (int c = 0; c < 17; ++c) {
                lds[c * D_ + d4 + 0] += acc[c].x;
                lds[c * D_ + d4 + 1] += acc[c].y;
                lds[c * D_ + d4 + 2] += acc[c].z;
                lds[c * D_ + d4 + 3] += acc[c].w;
            }
        }
        __syncthreads();
    }

    // one coalesced atomicAdd stream per block (16 contributors per address)
    const float scale = 1.0f / (float)N_;
    float* __restrict__ ob = out + (size_t)b * 17 * D_;
#pragma unroll
    for (int c = 0; c < 17; ++c) {
        atomicAdd(&ob[c * D_ + tid], lds[c * D_ + tid] * scale);
    }
}

extern "C" void kernel_launch(void* const* d_in, const int* in_sizes, int n_in,
                              void* d_out, int out_size, void* d_ws, size_t ws_size,
                              hipStream_t stream) {
    const float* r = (const float*)d_in[0];   // (B,N,C) fp32
    const float* v = (const float*)d_in[1];   // (B,N,D) fp32
    float* out = (float*)d_out;               // (B,C+1,D) fp32

    // harness re-poisons d_out to 0xAA before every timed launch
    hipMemsetAsync(out, 0, (size_t)out_size * sizeof(float), stream);

    dim3 grid(B_ * NSPLIT);
    tensor_fusion_kernel<<<grid, 256, 0, stream>>>(r, v, out);
}